// Round 5
// baseline (275.058 us; speedup 1.0000x reference)
//
#include <hip/hip_runtime.h>
#include <hip/hip_bf16.h>

#define N_USERS   100000
#define EMBED_DIM 128
#define N_EDGES   640000

typedef __bf16 bf16x8 __attribute__((ext_vector_type(8)));
typedef float  f32x4  __attribute__((ext_vector_type(4)));

// ---- workspace layout (bytes) ----
// [0,          25,600,000)  embb   bf16 [100000][128] (emb rounded to bf16)
// [25,600,000, 26,000,000)  counts int  [100000]
// [26,000,000, 26,000,004)  total  int  [1]     (zeroed together with counts)
// [26,000,128, 26,400,128)  start  int  [100000]
// [26,400,128, 26,800,128)  cursor int  [100000]
// [26,800,128, 29,360,128)  perm   int  [640000] (src ids grouped by dst)
// [29,360,128, 29,392,896)  wlb    bf16 [128][128]
// [29,392,896, 29,425,664)  wrb    bf16 [128][128]
#define OFF_COUNTS 25600000
#define OFF_TOTAL  26000000
#define OFF_START  26000128
#define OFF_CURSOR 26400128
#define OFF_PERM   26800128
#define OFF_WLB    29360128
#define OFF_WRB    29392896

__device__ __forceinline__ unsigned short f2bf_rne(float f) {
    union { float f; unsigned u; } c; c.f = f;
    unsigned u = c.u + 0x7fffu + ((c.u >> 16) & 1u);
    return (unsigned short)(u >> 16);
}
__device__ __forceinline__ float bf2f_lo(unsigned u) {
    union { float f; unsigned u; } c; c.u = u << 16;
    return c.f;
}
__device__ __forceinline__ float bf2f_hi(unsigned u) {
    union { float f; unsigned u; } c; c.u = u & 0xffff0000u;
    return c.f;
}

// Convert W_l/W_r -> bf16, emb -> embb (bf16), and dst histogram.
// counts/total are pre-zeroed by hipMemsetAsync (stream-ordered before us).
// grid: 6250 x 256 (1.6M threads x 8 floats = 12.8M = full emb table)
__global__ __launch_bounds__(256) void k_init(const float* __restrict__ emb,
                                              const float* __restrict__ Wl,
                                              const float* __restrict__ Wr,
                                              const int* __restrict__ dst,
                                              unsigned short* __restrict__ embb,
                                              int* __restrict__ counts,
                                              unsigned short* __restrict__ wlb,
                                              unsigned short* __restrict__ wrb) {
    int i = blockIdx.x * 256 + threadIdx.x;
    if (i < 4096) {    // 16384 floats per W matrix / 4
        float4 a = ((const float4*)Wl)[i];
        float4 b = ((const float4*)Wr)[i];
        int o = i * 4;
        wlb[o+0] = f2bf_rne(a.x); wlb[o+1] = f2bf_rne(a.y);
        wlb[o+2] = f2bf_rne(a.z); wlb[o+3] = f2bf_rne(a.w);
        wrb[o+0] = f2bf_rne(b.x); wrb[o+1] = f2bf_rne(b.y);
        wrb[o+2] = f2bf_rne(b.z); wrb[o+3] = f2bf_rne(b.w);
    }
    // emb -> embb, 8 floats per thread
    float4 a = ((const float4*)emb)[i * 2 + 0];
    float4 b = ((const float4*)emb)[i * 2 + 1];
    int4 p;
    p.x = (int)f2bf_rne(a.x) | ((int)f2bf_rne(a.y) << 16);
    p.y = (int)f2bf_rne(a.z) | ((int)f2bf_rne(a.w) << 16);
    p.z = (int)f2bf_rne(b.x) | ((int)f2bf_rne(b.y) << 16);
    p.w = (int)f2bf_rne(b.z) | ((int)f2bf_rne(b.w) << 16);
    ((int4*)embb)[i] = p;
    // dst histogram (overlaps with the streaming conversion)
    if (i < N_EDGES) atomicAdd(&counts[dst[i]], 1);
}

// Exclusive allocation of contiguous per-node regions (order arbitrary).
// grid: 98 x 256
__global__ __launch_bounds__(256) void k_alloc(const int* __restrict__ counts,
                                               int* __restrict__ start,
                                               int* __restrict__ cursor,
                                               int* __restrict__ total) {
    int i    = blockIdx.x * 256 + threadIdx.x;
    int lane = threadIdx.x & 63;
    int wv   = threadIdx.x >> 6;
    int4 c4 = {0, 0, 0, 0};
    if (i < 25000) c4 = ((const int4*)counts)[i];
    int csum = c4.x + c4.y + c4.z + c4.w;
    int pre = csum;
#pragma unroll
    for (int d = 1; d < 64; d <<= 1) {
        int v = __shfl_up(pre, d);
        if (lane >= d) pre += v;
    }
    __shared__ int swv[4];
    __shared__ int sgbase;
    if (lane == 63) swv[wv] = pre;
    __syncthreads();
    if (threadIdx.x == 0)
        sgbase = atomicAdd(total, swv[0] + swv[1] + swv[2] + swv[3]);
    __syncthreads();
    int waveoff = 0;
    for (int w = 0; w < wv; w++) waveoff += swv[w];
    int base = sgbase + waveoff + (pre - csum);
    if (i < 25000) {
        int4 s;
        s.x = base;
        s.y = s.x + c4.x;
        s.z = s.y + c4.y;
        s.w = s.z + c4.z;
        ((int4*)start)[i]  = s;
        ((int4*)cursor)[i] = s;
    }
}

// Scatter edge src-ids into dst-grouped buckets.  grid: 2500 x 256
__global__ __launch_bounds__(256) void k_perm(const int* __restrict__ src,
                                              const int* __restrict__ dst,
                                              int* __restrict__ cursor,
                                              int* __restrict__ perm) {
    int e = blockIdx.x * 256 + threadIdx.x;
    if (e < N_EDGES) {
        int pos = atomicAdd(&cursor[dst[e]], 1);
        perm[pos] = src[e];
    }
}

// Fused mean-aggregation + dual GEMM.  One block = 16 nodes.
// Phase 1: each of 4 waves gathers+means 4 nodes (2 bf16/lane) into LDS.
// Phase 2: each wave MFMAs its 2 column-tiles; W fragments register-resident
// (loads issued before phase 1 so they're in flight during the gather).
// LDS row stride 136 bf16 (+8 pad): MFMA frag read drops 16-way -> 8-way max.
// grid: 6250 x 256
#define LDS_STRIDE 136
__global__ __launch_bounds__(256, 3) void k_fused(const unsigned short* __restrict__ embb,
                                                  const int* __restrict__ start,
                                                  const int* __restrict__ counts,
                                                  const int* __restrict__ perm,
                                                  const unsigned short* __restrict__ wlb,
                                                  const unsigned short* __restrict__ wrb,
                                                  const float* __restrict__ bl,
                                                  float* __restrict__ out) {
    __shared__ unsigned short smean[16 * LDS_STRIDE];
    int wave = threadIdx.x >> 6;
    int lane = threadIdx.x & 63;
    int quad = lane >> 4;      // 0..3
    int m    = lane & 15;
    int jt0  = wave * 2;       // this wave's two column tiles
    int node0 = blockIdx.x * 16;

    // Register-resident B fragments: B[n=m][k = kt*32 + quad*8 + j]
    bf16x8 wl[2][4], wr[2][4];
#pragma unroll
    for (int jj = 0; jj < 2; jj++) {
#pragma unroll
        for (int kt = 0; kt < 4; kt++) {
            size_t off = (size_t)((jt0 + jj) * 16 + m) * EMBED_DIM + kt * 32 + quad * 8;
            wl[jj][kt] = *(const bf16x8*)((const __bf16*)wlb + off);
            wr[jj][kt] = *(const bf16x8*)((const __bf16*)wrb + off);
        }
    }
    float bias[2];
    bias[0] = bl[(jt0 + 0) * 16 + m];
    bias[1] = bl[(jt0 + 1) * 16 + m];

    // ---- Phase 1: aggregate 4 nodes per wave ----
#pragma unroll
    for (int q = 0; q < 4; q++) {
        int nl   = wave * 4 + q;       // local node 0..15
        int node = node0 + nl;
        int s0  = start[node];
        int cnt = counts[node];
        float2 acc = {0.f, 0.f};
        int i = 0;
        for (; i + 3 < cnt; i += 4) {  // 4 rows in flight
            int sa = perm[s0 + i + 0];
            int sb = perm[s0 + i + 1];
            int sc = perm[s0 + i + 2];
            int sd = perm[s0 + i + 3];
            unsigned va = *(const unsigned*)(embb + (size_t)sa * EMBED_DIM + lane * 2);
            unsigned vb = *(const unsigned*)(embb + (size_t)sb * EMBED_DIM + lane * 2);
            unsigned vc = *(const unsigned*)(embb + (size_t)sc * EMBED_DIM + lane * 2);
            unsigned vd = *(const unsigned*)(embb + (size_t)sd * EMBED_DIM + lane * 2);
            acc.x += (bf2f_lo(va) + bf2f_lo(vb)) + (bf2f_lo(vc) + bf2f_lo(vd));
            acc.y += (bf2f_hi(va) + bf2f_hi(vb)) + (bf2f_hi(vc) + bf2f_hi(vd));
        }
        for (; i < cnt; i++) {
            int sa = perm[s0 + i];
            unsigned va = *(const unsigned*)(embb + (size_t)sa * EMBED_DIM + lane * 2);
            acc.x += bf2f_lo(va);
            acc.y += bf2f_hi(va);
        }
        float inv = (cnt > 0) ? 1.0f / (float)cnt : 0.0f;
        unsigned o = (unsigned)f2bf_rne(acc.x * inv) | ((unsigned)f2bf_rne(acc.y * inv) << 16);
        *(unsigned*)(smean + nl * LDS_STRIDE + lane * 2) = o;
    }
    __syncthreads();

    // ---- Phase 2: 16x128 output tile, this wave's 2 column tiles ----
    const __bf16* erow = (const __bf16*)embb + (size_t)(node0 + m) * EMBED_DIM;
    bf16x8 af[4], ef[4];
#pragma unroll
    for (int kt = 0; kt < 4; kt++) {
        int kb = kt * 32 + quad * 8;
        af[kt] = *(const bf16x8*)((const __bf16*)smean + m * LDS_STRIDE + kb);
        ef[kt] = *(const bf16x8*)(erow + kb);
    }

    f32x4 acc[2] = {{0.f,0.f,0.f,0.f}, {0.f,0.f,0.f,0.f}};
#pragma unroll
    for (int kt = 0; kt < 4; kt++) {
#pragma unroll
        for (int jj = 0; jj < 2; jj++) {
            acc[jj] = __builtin_amdgcn_mfma_f32_16x16x32_bf16(af[kt], wl[jj][kt], acc[jj], 0, 0, 0);
            acc[jj] = __builtin_amdgcn_mfma_f32_16x16x32_bf16(ef[kt], wr[jj][kt], acc[jj], 0, 0, 0);
        }
    }

    // C/D layout: col = lane&15, row = quad*4 + reg
#pragma unroll
    for (int jj = 0; jj < 2; jj++) {
#pragma unroll
        for (int r = 0; r < 4; r++) {
            int orow = node0 + quad * 4 + r;
            out[(size_t)orow * EMBED_DIM + (jt0 + jj) * 16 + m] = acc[jj][r] + bias[jj];
        }
    }
}

extern "C" void kernel_launch(void* const* d_in, const int* in_sizes, int n_in,
                              void* d_out, int out_size, void* d_ws, size_t ws_size,
                              hipStream_t stream) {
    const float* emb = (const float*)d_in[0];
    const float* Wl  = (const float*)d_in[1];
    const float* bl  = (const float*)d_in[2];
    const float* Wr  = (const float*)d_in[3];
    const int*   src = (const int*)d_in[4];
    const int*   dst = (const int*)d_in[5];
    float* out = (float*)d_out;

    char* ws = (char*)d_ws;
    unsigned short* embb   = (unsigned short*)ws;
    int*            counts = (int*)(ws + OFF_COUNTS);
    int*            total  = (int*)(ws + OFF_TOTAL);
    int*            start  = (int*)(ws + OFF_START);
    int*            cursor = (int*)(ws + OFF_CURSOR);
    int*            perm   = (int*)(ws + OFF_PERM);
    unsigned short* wlb    = (unsigned short*)(ws + OFF_WLB);
    unsigned short* wrb    = (unsigned short*)(ws + OFF_WRB);

    // zero counts + total (graph-capturable memset node; stream-ordered
    // before k_init's histogram atomics)
    hipMemsetAsync(ws + OFF_COUNTS, 0, (OFF_TOTAL - OFF_COUNTS) + 4, stream);

    k_init<<<6250, 256, 0, stream>>>(emb, Wl, Wr, dst, embb, counts, wlb, wrb);
    k_alloc<<<98, 256, 0, stream>>>(counts, start, cursor, total);
    k_perm<<<2500, 256, 0, stream>>>(src, dst, cursor, perm);
    k_fused<<<6250, 256, 0, stream>>>(embb, start, counts, perm, wlb, wrb, bl, out);
}

// Round 7
// 235.857 us; speedup vs baseline: 1.1662x; 1.1662x over previous
//
#include <hip/hip_runtime.h>
#include <hip/hip_bf16.h>

#define N_USERS   100000
#define EMBED_DIM 128
#define N_EDGES   640000
#define ZERO_ROW  N_USERS          // embb row of zeros for padded edge slots

typedef __bf16 bf16x8 __attribute__((ext_vector_type(8)));
typedef float  f32x4  __attribute__((ext_vector_type(4)));

// ---- workspace layout (bytes) ----
// [0,          25,600,256)  embb   bf16 [100001][128] (row 100000 = zeros)
// [25,600,256, 26,000,256)  counts int  [100000]
// [26,000,256, 26,000,260)  total  int  [1]   (memset together with counts)
// [26,000,384, 26,400,384)  start  int  [100000]  (padded CSR starts, 4-aligned)
// [26,400,384, 26,800,384)  cursor int  [100000]
// [26,800,384, 30,560,384)  perm   int  [940000 max] (src ids grouped by dst,
//                                                     padded to x4 with ZERO_ROW)
// [30,560,384, 30,593,152)  wlb    bf16 [128][128]
// [30,593,152, 30,625,920)  wrb    bf16 [128][128]
// [30,625,920, 56,225,920)  aggb   bf16 [100000][128]
#define OFF_COUNTS 25600256
#define OFF_TOTAL  26000256
#define OFF_START  26000384
#define OFF_CURSOR 26400384
#define OFF_PERM   26800384
#define OFF_WLB    30560384
#define OFF_WRB    30593152
#define OFF_AGGB   30625920

__device__ __forceinline__ unsigned short f2bf_rne(float f) {
    union { float f; unsigned u; } c; c.f = f;
    unsigned u = c.u + 0x7fffu + ((c.u >> 16) & 1u);
    return (unsigned short)(u >> 16);
}
__device__ __forceinline__ float bf2f_lo(unsigned u) {
    union { float f; unsigned u; } c; c.u = u << 16;
    return c.f;
}
__device__ __forceinline__ float bf2f_hi(unsigned u) {
    union { float f; unsigned u; } c; c.u = u & 0xffff0000u;
    return c.f;
}

// Convert W_l/W_r -> bf16, emb -> embb (bf16), zero-row, dst histogram.
// counts/total pre-zeroed by hipMemsetAsync (stream-ordered before us).
// grid: 6250 x 256
__global__ __launch_bounds__(256) void k_init(const float* __restrict__ emb,
                                              const float* __restrict__ Wl,
                                              const float* __restrict__ Wr,
                                              const int* __restrict__ dst,
                                              unsigned short* __restrict__ embb,
                                              int* __restrict__ counts,
                                              unsigned short* __restrict__ wlb,
                                              unsigned short* __restrict__ wrb) {
    int i = blockIdx.x * 256 + threadIdx.x;
    if (i < 4096) {    // 16384 floats per W matrix / 4
        float4 a = ((const float4*)Wl)[i];
        float4 b = ((const float4*)Wr)[i];
        int o = i * 4;
        wlb[o+0] = f2bf_rne(a.x); wlb[o+1] = f2bf_rne(a.y);
        wlb[o+2] = f2bf_rne(a.z); wlb[o+3] = f2bf_rne(a.w);
        wrb[o+0] = f2bf_rne(b.x); wrb[o+1] = f2bf_rne(b.y);
        wrb[o+2] = f2bf_rne(b.z); wrb[o+3] = f2bf_rne(b.w);
    }
    // zero row at index N_USERS: 128 bf16 = 256 B = exactly 16 int4.
    // (Round-6 bug: 32 int4 overran 256 B into counts[], racing the
    // histogram atomics below.)
    if (i < 16) {
        int4 z = {0, 0, 0, 0};
        ((int4*)(embb + (size_t)ZERO_ROW * EMBED_DIM))[i] = z;
    }
    // emb -> embb, 8 floats per thread
    float4 a = ((const float4*)emb)[i * 2 + 0];
    float4 b = ((const float4*)emb)[i * 2 + 1];
    int4 p;
    p.x = (int)f2bf_rne(a.x) | ((int)f2bf_rne(a.y) << 16);
    p.y = (int)f2bf_rne(a.z) | ((int)f2bf_rne(a.w) << 16);
    p.z = (int)f2bf_rne(b.x) | ((int)f2bf_rne(b.y) << 16);
    p.w = (int)f2bf_rne(b.z) | ((int)f2bf_rne(b.w) << 16);
    ((int4*)embb)[i] = p;
    // dst histogram (overlaps with the streaming conversion)
    if (i < N_EDGES) atomicAdd(&counts[dst[i]], 1);
}

// Exclusive allocation of contiguous per-node regions, PADDED to multiples
// of 4; fill pad slots of perm with ZERO_ROW.  grid: 98 x 256
__global__ __launch_bounds__(256) void k_alloc(const int* __restrict__ counts,
                                               int* __restrict__ start,
                                               int* __restrict__ cursor,
                                               int* __restrict__ total,
                                               int* __restrict__ perm) {
    int i    = blockIdx.x * 256 + threadIdx.x;
    int lane = threadIdx.x & 63;
    int wv   = threadIdx.x >> 6;
    int4 c4 = {0, 0, 0, 0};
    if (i < 25000) c4 = ((const int4*)counts)[i];
    int4 p4;                       // padded counts
    p4.x = (c4.x + 3) & ~3;
    p4.y = (c4.y + 3) & ~3;
    p4.z = (c4.z + 3) & ~3;
    p4.w = (c4.w + 3) & ~3;
    int csum = p4.x + p4.y + p4.z + p4.w;
    int pre = csum;
#pragma unroll
    for (int d = 1; d < 64; d <<= 1) {
        int v = __shfl_up(pre, d);
        if (lane >= d) pre += v;
    }
    __shared__ int swv[4];
    __shared__ int sgbase;
    if (lane == 63) swv[wv] = pre;
    __syncthreads();
    if (threadIdx.x == 0)
        sgbase = atomicAdd(total, swv[0] + swv[1] + swv[2] + swv[3]);
    __syncthreads();
    int waveoff = 0;
    for (int w = 0; w < wv; w++) waveoff += swv[w];
    int base = sgbase + waveoff + (pre - csum);
    if (i < 25000) {
        int4 s;
        s.x = base;
        s.y = s.x + p4.x;
        s.z = s.y + p4.y;
        s.w = s.z + p4.z;
        ((int4*)start)[i]  = s;
        ((int4*)cursor)[i] = s;
        // fill pad slots with ZERO_ROW
        for (int k = c4.x; k < p4.x; k++) perm[s.x + k] = ZERO_ROW;
        for (int k = c4.y; k < p4.y; k++) perm[s.y + k] = ZERO_ROW;
        for (int k = c4.z; k < p4.z; k++) perm[s.z + k] = ZERO_ROW;
        for (int k = c4.w; k < p4.w; k++) perm[s.w + k] = ZERO_ROW;
    }
}

// Scatter edge src-ids into dst-grouped buckets.  grid: 2500 x 256
__global__ __launch_bounds__(256) void k_perm(const int* __restrict__ src,
                                              const int* __restrict__ dst,
                                              int* __restrict__ cursor,
                                              int* __restrict__ perm) {
    int e = blockIdx.x * 256 + threadIdx.x;
    if (e < N_EDGES) {
        int pos = atomicAdd(&cursor[dst[e]], 1);
        perm[pos] = src[e];
    }
}

// Gather-side mean aggregation: one wave per 2 nodes (interleaved chains,
// 8 row-loads in flight), padded x4 edge lists (no serialized remainder),
// int4 perm loads, fp32 accumulate, pre-divide, store bf16.
// grid: 12500 x 256 (4 waves -> 8 nodes per block)
__global__ __launch_bounds__(256) void k_aggregate(const unsigned short* __restrict__ embb,
                                                   const int* __restrict__ start,
                                                   const int* __restrict__ counts,
                                                   const int* __restrict__ perm,
                                                   unsigned short* __restrict__ aggb) {
    int gw   = (blockIdx.x * 256 + threadIdx.x) >> 6;   // 0..49999
    int lane = threadIdx.x & 63;
    int nA = gw * 2;
    int nB = nA + 1;
    int sA = start[nA], cntA = counts[nA];
    int sB = start[nB], cntB = counts[nB];
    int ga = (cntA + 3) >> 2;      // padded groups of 4
    int gb = (cntB + 3) >> 2;
    int gmin = ga < gb ? ga : gb;
    float2 accA = {0.f, 0.f}, accB = {0.f, 0.f};
    const unsigned short* ep = embb;
    int off = lane * 2;

    int t = 0;
    for (; t < gmin; t++) {                 // 8 rows in flight
        int4 ia = ((const int4*)(perm + sA))[t];
        int4 ib = ((const int4*)(perm + sB))[t];
        unsigned a0 = *(const unsigned*)(ep + (size_t)ia.x * EMBED_DIM + off);
        unsigned a1 = *(const unsigned*)(ep + (size_t)ia.y * EMBED_DIM + off);
        unsigned a2 = *(const unsigned*)(ep + (size_t)ia.z * EMBED_DIM + off);
        unsigned a3 = *(const unsigned*)(ep + (size_t)ia.w * EMBED_DIM + off);
        unsigned b0 = *(const unsigned*)(ep + (size_t)ib.x * EMBED_DIM + off);
        unsigned b1 = *(const unsigned*)(ep + (size_t)ib.y * EMBED_DIM + off);
        unsigned b2 = *(const unsigned*)(ep + (size_t)ib.z * EMBED_DIM + off);
        unsigned b3 = *(const unsigned*)(ep + (size_t)ib.w * EMBED_DIM + off);
        accA.x += (bf2f_lo(a0) + bf2f_lo(a1)) + (bf2f_lo(a2) + bf2f_lo(a3));
        accA.y += (bf2f_hi(a0) + bf2f_hi(a1)) + (bf2f_hi(a2) + bf2f_hi(a3));
        accB.x += (bf2f_lo(b0) + bf2f_lo(b1)) + (bf2f_lo(b2) + bf2f_lo(b3));
        accB.y += (bf2f_hi(b0) + bf2f_hi(b1)) + (bf2f_hi(b2) + bf2f_hi(b3));
    }
    for (int ta = t; ta < ga; ta++) {
        int4 ia = ((const int4*)(perm + sA))[ta];
        unsigned a0 = *(const unsigned*)(ep + (size_t)ia.x * EMBED_DIM + off);
        unsigned a1 = *(const unsigned*)(ep + (size_t)ia.y * EMBED_DIM + off);
        unsigned a2 = *(const unsigned*)(ep + (size_t)ia.z * EMBED_DIM + off);
        unsigned a3 = *(const unsigned*)(ep + (size_t)ia.w * EMBED_DIM + off);
        accA.x += (bf2f_lo(a0) + bf2f_lo(a1)) + (bf2f_lo(a2) + bf2f_lo(a3));
        accA.y += (bf2f_hi(a0) + bf2f_hi(a1)) + (bf2f_hi(a2) + bf2f_hi(a3));
    }
    for (int tb = t; tb < gb; tb++) {
        int4 ib = ((const int4*)(perm + sB))[tb];
        unsigned b0 = *(const unsigned*)(ep + (size_t)ib.x * EMBED_DIM + off);
        unsigned b1 = *(const unsigned*)(ep + (size_t)ib.y * EMBED_DIM + off);
        unsigned b2 = *(const unsigned*)(ep + (size_t)ib.z * EMBED_DIM + off);
        unsigned b3 = *(const unsigned*)(ep + (size_t)ib.w * EMBED_DIM + off);
        accB.x += (bf2f_lo(b0) + bf2f_lo(b1)) + (bf2f_lo(b2) + bf2f_lo(b3));
        accB.y += (bf2f_hi(b0) + bf2f_hi(b1)) + (bf2f_hi(b2) + bf2f_hi(b3));
    }
    float invA = (cntA > 0) ? 1.0f / (float)cntA : 0.0f;
    float invB = (cntB > 0) ? 1.0f / (float)cntB : 0.0f;
    unsigned oA = (unsigned)f2bf_rne(accA.x * invA) | ((unsigned)f2bf_rne(accA.y * invA) << 16);
    unsigned oB = (unsigned)f2bf_rne(accB.x * invB) | ((unsigned)f2bf_rne(accB.y * invB) << 16);
    *(unsigned*)(aggb + (size_t)nA * EMBED_DIM + off) = oA;
    *(unsigned*)(aggb + (size_t)nB * EMBED_DIM + off) = oB;
}

// out[n][j] = sum_k aggb[n][k]*Wl[j][k] + embb[n][k]*Wr[j][k] + bl[j]
// Each wave owns 2 of 8 column-tiles with B-fragments register-resident,
// iterates over 5 row-tiles.  grid: 1250 x 256
#define TILES_PER_BLOCK 5
__global__ __launch_bounds__(256, 4) void k_matmul(const unsigned short* __restrict__ aggb,
                                                   const unsigned short* __restrict__ wlb,
                                                   const unsigned short* __restrict__ wrb,
                                                   const unsigned short* __restrict__ embb,
                                                   const float* __restrict__ bl,
                                                   float* __restrict__ out) {
    int wave = threadIdx.x >> 6;
    int lane = threadIdx.x & 63;
    int quad = lane >> 4;      // 0..3
    int m    = lane & 15;
    int jt0  = wave * 2;       // this wave's two column tiles

    // Register-resident B fragments: B[n=m][k = kt*32 + quad*8 + j]
    bf16x8 wl[2][4], wr[2][4];
#pragma unroll
    for (int jj = 0; jj < 2; jj++) {
#pragma unroll
        for (int kt = 0; kt < 4; kt++) {
            size_t off = (size_t)((jt0 + jj) * 16 + m) * EMBED_DIM + kt * 32 + quad * 8;
            wl[jj][kt] = *(const bf16x8*)((const __bf16*)wlb + off);
            wr[jj][kt] = *(const bf16x8*)((const __bf16*)wrb + off);
        }
    }
    float bias[2];
    bias[0] = bl[(jt0 + 0) * 16 + m];
    bias[1] = bl[(jt0 + 1) * 16 + m];

    int tile0 = blockIdx.x * TILES_PER_BLOCK;
#pragma unroll
    for (int t = 0; t < TILES_PER_BLOCK; t++) {
        int row0 = (tile0 + t) * 16;
        int node = row0 + m;
        const __bf16* arow = (const __bf16*)aggb + (size_t)node * EMBED_DIM;
        const __bf16* erow = (const __bf16*)embb + (size_t)node * EMBED_DIM;

        bf16x8 af[4], ef[4];
#pragma unroll
        for (int kt = 0; kt < 4; kt++) {
            int kb = kt * 32 + quad * 8;
            af[kt] = *(const bf16x8*)(arow + kb);
            ef[kt] = *(const bf16x8*)(erow + kb);
        }

        f32x4 acc[2] = {{0.f,0.f,0.f,0.f}, {0.f,0.f,0.f,0.f}};
#pragma unroll
        for (int kt = 0; kt < 4; kt++) {
#pragma unroll
            for (int jj = 0; jj < 2; jj++) {
                acc[jj] = __builtin_amdgcn_mfma_f32_16x16x32_bf16(af[kt], wl[jj][kt], acc[jj], 0, 0, 0);
                acc[jj] = __builtin_amdgcn_mfma_f32_16x16x32_bf16(ef[kt], wr[jj][kt], acc[jj], 0, 0, 0);
            }
        }

        // C/D layout: col = lane&15, row = quad*4 + reg
#pragma unroll
        for (int jj = 0; jj < 2; jj++) {
#pragma unroll
            for (int r = 0; r < 4; r++) {
                int orow = row0 + quad * 4 + r;
                out[(size_t)orow * EMBED_DIM + (jt0 + jj) * 16 + m] = acc[jj][r] + bias[jj];
            }
        }
    }
}

extern "C" void kernel_launch(void* const* d_in, const int* in_sizes, int n_in,
                              void* d_out, int out_size, void* d_ws, size_t ws_size,
                              hipStream_t stream) {
    const float* emb = (const float*)d_in[0];
    const float* Wl  = (const float*)d_in[1];
    const float* bl  = (const float*)d_in[2];
    const float* Wr  = (const float*)d_in[3];
    const int*   src = (const int*)d_in[4];
    const int*   dst = (const int*)d_in[5];
    float* out = (float*)d_out;

    char* ws = (char*)d_ws;
    unsigned short* embb   = (unsigned short*)ws;
    int*            counts = (int*)(ws + OFF_COUNTS);
    int*            total  = (int*)(ws + OFF_TOTAL);
    int*            start  = (int*)(ws + OFF_START);
    int*            cursor = (int*)(ws + OFF_CURSOR);
    int*            perm   = (int*)(ws + OFF_PERM);
    unsigned short* wlb    = (unsigned short*)(ws + OFF_WLB);
    unsigned short* wrb    = (unsigned short*)(ws + OFF_WRB);
    unsigned short* aggb   = (unsigned short*)(ws + OFF_AGGB);

    // zero counts + total (graph-capturable memset node)
    hipMemsetAsync(ws + OFF_COUNTS, 0, (OFF_TOTAL - OFF_COUNTS) + 4, stream);

    k_init<<<6250, 256, 0, stream>>>(emb, Wl, Wr, dst, embb, counts, wlb, wrb);
    k_alloc<<<98, 256, 0, stream>>>(counts, start, cursor, total, perm);
    k_perm<<<2500, 256, 0, stream>>>(src, dst, cursor, perm);
    k_aggregate<<<12500, 256, 0, stream>>>(embb, start, counts, perm, aggb);
    k_matmul<<<1250, 256, 0, stream>>>(aggb, wlb, wrb, embb, bl, out);
}